// Round 2
// baseline (4555.042 us; speedup 1.0000x reference)
//
#include <hip/hip_runtime.h>
#include <hip/hip_bf16.h>
#include <stdint.h>

// Problem dims
#define BATCH 256
#define SEQ   512
#define INDIM 64
#define H     128
#define RB    4               // batch rows per tile (valid C-rows at quad*4, r=0)
#define NTILE (BATCH / RB)    // 64 blocks, one per batch tile (both layers inside)

using short8  = __attribute__((ext_vector_type(8))) short;  // 8 bf16 MFMA A/B frag
using float4v = __attribute__((ext_vector_type(4))) float;  // MFMA C/D frag

#define LOG2E 1.4426950408889634f

__device__ __forceinline__ unsigned short f2bf(float f) {
    union { float f; uint32_t u; } v; v.f = f;
    uint32_t u = v.u;
    return (unsigned short)((u + 0x7FFFu + ((u >> 16) & 1u)) >> 16); // RNE
}

__device__ __forceinline__ float fast_exp2(float x) {
#if __has_builtin(__builtin_amdgcn_exp2f)
    return __builtin_amdgcn_exp2f(x);
#else
    return __expf(x * 0.6931471805599453f);
#endif
}
__device__ __forceinline__ float fast_rcp(float x) {
#if __has_builtin(__builtin_amdgcn_rcpf)
    return __builtin_amdgcn_rcpf(x);
#else
    return 1.f / x;
#endif
}
__device__ __forceinline__ float sigmoid_fast(float x) {
    return fast_rcp(1.f + fast_exp2(-LOG2E * x));
}
__device__ __forceinline__ float tanh_fast(float x) {
    return fmaf(-2.f, fast_rcp(1.f + fast_exp2((2.f * LOG2E) * x)), 1.f);
}

// Per-interval barrier: LDS ordering only (lgkmcnt). Global x-prefetch loads
// stay in flight across it. No vmcnt drain anywhere in the main loop.
__device__ __forceinline__ void light_barrier() {
    asm volatile("s_waitcnt lgkmcnt(0)\n\ts_barrier" ::: "memory");
}

// ---------------- x fp32 -> bf16 convert ----------------
__global__ void conv_x_kernel(const float* __restrict__ x,
                              unsigned short* __restrict__ xb, int n4) {
    int i = blockIdx.x * blockDim.x + threadIdx.x;
    if (i >= n4) return;
    float4 f = ((const float4*)x)[i];
    ushort4 o;
    o.x = f2bf(f.x); o.y = f2bf(f.y); o.z = f2bf(f.z); o.w = f2bf(f.w);
    ((ushort4*)xb)[i] = o;
}

// ---------------- fully fused 2-layer LSTM + head, one block per tile ------
// 64 blocks x 1024 threads. Waves 0..7: layer0 (producer), waves 8..15:
// layer1 (consumer). h0 passes through LDS double buffers with skew-1:
// interval s: producer computes h0(s) [reads h0b[(s-1)&1], writes h0b[s&1]];
// consumer computes h1(s-1) [reads h0b[(s-1)&1] and h1b[s&1], writes
// h1b[(s-1)&1]]. One lgkm-only barrier per interval; 513 intervals total.
// Why: R0 step time was ~2000cy with only ~700cy of pipe work (2 waves/SIMD,
// phase-locked) -> 4 mixed waves/SIMD fill the stalls; also deletes the 32MB
// h0sq round-trip, flag atomics, chunk refills, and the 16-step lag.
// R1 lesson: independence must come from MORE WAVES, not more state per wave
// (dual-tile-per-wave blew the register budget -> 707us). Per-wave register
// footprint here is identical to R0 (one layer role per wave).
// R5 lesson (still enforced): every per-thread register array is indexed
// ONLY with compile-time constants; double buffers are statically named.
__global__ __launch_bounds__(1024, 4)
void lstm_fused_kernel(const unsigned short* __restrict__ xb,
                       const float* __restrict__ Wih0, const float* __restrict__ Whh0,
                       const float* __restrict__ bih0, const float* __restrict__ bhh0,
                       const float* __restrict__ Wih1, const float* __restrict__ Whh1,
                       const float* __restrict__ bih1, const float* __restrict__ bhh1,
                       const float* __restrict__ W1, const float* __restrict__ b1,
                       const float* __restrict__ W2, const float* __restrict__ b2,
                       float* __restrict__ out)
{
    constexpr int PAD = 132;                 // 66 dwords == 2 mod 32 -> 2-way (free) aliasing
    const int bt   = blockIdx.x;
    const int w    = threadIdx.x >> 6;
    const bool prod = (w < 8);
    const int lane = threadIdx.x & 63;
    const int quad = lane >> 4;
    const int l16  = lane & 15;
    const int cell = (w & 7) * 16 + l16;
    const int arow = l16 & 12;               // LDS h row this lane reads (4-lane broadcast)
    const int b0   = bt * RB;

    __shared__ short h0b[2][16][PAD];        // layer0 h double buffer
    __shared__ short h1b[2][16][PAD];        // layer1 h double buffer
    __shared__ float hl[RB][128];            // fp32 h1_last (head input)
    __shared__ float mid[RB][65];
    for (int i = threadIdx.x; i < 2 * 16 * PAD; i += 1024) {
        ((short*)h0b)[i] = 0;
        ((short*)h1b)[i] = 0;
    }

    // ---- weight fragments (loaded once, fp32->bf16, persist in registers).
    //      Each wave loads only ITS layer's weights (role-selected pointers).
    const float* Wih = prod ? Wih0 : Wih1;
    const float* Whh = prod ? Whh0 : Whh1;
    const float* bi  = prod ? bih0 : bih1;
    const float* bh  = prod ? bhh0 : bhh1;
    const int KINr = prod ? INDIM : H;       // 64 or 128
    const int KTr  = KINr / 32;              // 2 or 4

    short8 whh_f[4][4];
    short8 wih_f[4][4];                      // producer uses [.][0..1] only
    float  bias[4];
#pragma unroll
    for (int tT = 0; tT < 4; tT++) {
        const int n = tT * 128 + cell;
#pragma unroll
        for (int kt = 0; kt < 4; kt++) {
            const float* p = Whh + (size_t)n * H + kt * 32 + quad * 8;
            float4 f0 = *(const float4*)p;
            float4 f1 = *(const float4*)(p + 4);
            short8 s;
            s[0]=f2bf(f0.x); s[1]=f2bf(f0.y); s[2]=f2bf(f0.z); s[3]=f2bf(f0.w);
            s[4]=f2bf(f1.x); s[5]=f2bf(f1.y); s[6]=f2bf(f1.z); s[7]=f2bf(f1.w);
            whh_f[tT][kt] = s;
        }
#pragma unroll
        for (int kt = 0; kt < 4; kt++) {
            if (kt < KTr) {                  // wave-uniform guard, static index
                const float* p = Wih + (size_t)n * KINr + kt * 32 + quad * 8;
                float4 f0 = *(const float4*)p;
                float4 f1 = *(const float4*)(p + 4);
                short8 s;
                s[0]=f2bf(f0.x); s[1]=f2bf(f0.y); s[2]=f2bf(f0.z); s[3]=f2bf(f0.w);
                s[4]=f2bf(f1.x); s[5]=f2bf(f1.y); s[6]=f2bf(f1.z); s[7]=f2bf(f1.w);
                wih_f[tT][kt] = s;
            }
        }
        bias[tT] = bi[n] + bh[n];
    }

    float c0 = 0.f;                          // this lane's single cell state
    __syncthreads();                         // h-buffer zero-init visible

    if (prod) {
        // ================= layer-0 wave =================
        const unsigned short* xp = xb + ((size_t)(b0 + (l16 >> 2)) * SEQ) * INDIM + quad * 8;
        short8  xf0[2], xf1[2];              // statically-named x double buffer
        float4v accA[4], accB[4];            // statically-named acc double buffer

        // prologue: x(0), x(1); accA = bias + x(0)-projection
#pragma unroll
        for (int kt = 0; kt < 2; kt++) {
            xf0[kt] = *(const short8*)(xp + kt * 32);
            xf1[kt] = *(const short8*)(xp + INDIM + kt * 32);
        }
#pragma unroll
        for (int tT = 0; tT < 4; tT++)
            accA[tT] = (float4v){bias[tT], bias[tT], bias[tT], bias[tT]};
#pragma unroll
        for (int tT = 0; tT < 4; tT++)
#pragma unroll
            for (int kt = 0; kt < 2; kt++)
                accA[tT] = __builtin_amdgcn_mfma_f32_16x16x32_bf16(xf0[kt], wih_f[tT][kt], accA[tT], 0, 0, 0);

        // one producer interval: h(t) from h(t-1); accUse holds bias+x(t);
        // computes accNext = bias + x(t+1)-proj; prefetches x(t+2) into xPre.
        auto prod_step = [&](int t, float4v (&accUse)[4], float4v (&accNext)[4],
                             short8 (&xPre)[2], short8 (&xNext)[2],
                             bool doPre, bool doNext) __attribute__((always_inline)) {
            const int rp = (t & 1) ^ 1;      // h0(t-1) lives in h0b[(t-1)&1]
            const int wp = t & 1;
            short8 ha[4];
#pragma unroll
            for (int kt = 0; kt < 4; kt++)
                ha[kt] = *(const short8*)&h0b[rp][arow][kt * 32 + quad * 8];
#pragma unroll
            for (int tT = 0; tT < 4; tT++)
#pragma unroll
                for (int kt = 0; kt < 4; kt++)
                    accUse[tT] = __builtin_amdgcn_mfma_f32_16x16x32_bf16(ha[kt], whh_f[tT][kt], accUse[tT], 0, 0, 0);
            float g0 = accUse[0][0], g1 = accUse[1][0], g2 = accUse[2][0], g3 = accUse[3][0];

            if (doPre) {
                const unsigned short* p = xp + (size_t)(t + 2) * INDIM;
#pragma unroll
                for (int kt = 0; kt < 2; kt++) xPre[kt] = *(const short8*)(p + kt * 32);
            }
            if (doNext) {
#pragma unroll
                for (int tT = 0; tT < 4; tT++)
                    accNext[tT] = (float4v){bias[tT], bias[tT], bias[tT], bias[tT]};
#pragma unroll
                for (int tT = 0; tT < 4; tT++)
#pragma unroll
                    for (int kt = 0; kt < 2; kt++)
                        accNext[tT] = __builtin_amdgcn_mfma_f32_16x16x32_bf16(xNext[kt], wih_f[tT][kt], accNext[tT], 0, 0, 0);
            }

            float si = sigmoid_fast(g0);
            float sf = sigmoid_fast(g1);
            float tg = tanh_fast(g2);
            float so = sigmoid_fast(g3);
            c0 = fmaf(sf, c0, si * tg);
            float h = so * tanh_fast(c0);
            h0b[wp][quad * 4][cell] = (short)f2bf(h);
        };

#pragma unroll 1
        for (int ds = 0; ds < 256; ++ds) {
            const int t = 2 * ds;
            prod_step(t,     accA, accB, xf0, xf1, t + 2 < SEQ, true);
            light_barrier();
            prod_step(t + 1, accB, accA, xf1, xf0, t + 3 < SEQ, t + 2 < SEQ);
            light_barrier();
        }
        light_barrier();                     // tail interval (consumer-only)
    } else {
        // ================= layer-1 wave =================
        // gate(t') = [bias + Wih1·h0(t')] + [Whh1·h1(t'-1)] as two PARALLEL
        // 4-deep MFMA chains (accP || accG) summed at extract.
        auto cons_step = [&](int tp) __attribute__((always_inline)) {
            const int p = tp & 1;
            short8 ha0[4], ha1[4];
#pragma unroll
            for (int kt = 0; kt < 4; kt++)
                ha0[kt] = *(const short8*)&h0b[p][arow][kt * 32 + quad * 8];
#pragma unroll
            for (int kt = 0; kt < 4; kt++)
                ha1[kt] = *(const short8*)&h1b[p ^ 1][arow][kt * 32 + quad * 8];
            float4v accP[4], accG[4];
#pragma unroll
            for (int tT = 0; tT < 4; tT++) {
                accP[tT] = (float4v){bias[tT], bias[tT], bias[tT], bias[tT]};
                accG[tT] = (float4v){0.f, 0.f, 0.f, 0.f};
            }
#pragma unroll
            for (int tT = 0; tT < 4; tT++)
#pragma unroll
                for (int kt = 0; kt < 4; kt++) {
                    accP[tT] = __builtin_amdgcn_mfma_f32_16x16x32_bf16(ha0[kt], wih_f[tT][kt], accP[tT], 0, 0, 0);
                    accG[tT] = __builtin_amdgcn_mfma_f32_16x16x32_bf16(ha1[kt], whh_f[tT][kt], accG[tT], 0, 0, 0);
                }
            float g0 = accP[0][0] + accG[0][0];
            float g1 = accP[1][0] + accG[1][0];
            float g2 = accP[2][0] + accG[2][0];
            float g3 = accP[3][0] + accG[3][0];

            float si = sigmoid_fast(g0);
            float sf = sigmoid_fast(g1);
            float tg = tanh_fast(g2);
            float so = sigmoid_fast(g3);
            c0 = fmaf(sf, c0, si * tg);
            float h = so * tanh_fast(c0);
            h1b[p][quad * 4][cell] = (short)f2bf(h);
            if (tp == SEQ - 1) hl[quad][cell] = h;
        };

#pragma unroll 1
        for (int ds = 0; ds < 256; ++ds) {
            const int t = 2 * ds;
            if (ds > 0) cons_step(t - 1);    // skip at interval 0 (no h0 yet)
            light_barrier();
            cons_step(t);
            light_barrier();
        }
        cons_step(SEQ - 1);                  // tail interval
        light_barrier();
    }

    // ---- MLP head for this block's RB rows (hl visible via last barrier)
    if (threadIdx.x < RB * 64) {
        const int row = threadIdx.x >> 6, j = threadIdx.x & 63;
        float s = b1[j];
        const float* wr = W1 + (size_t)j * 128;
#pragma unroll 8
        for (int k = 0; k < 128; k++) s = fmaf(hl[row][k], wr[k], s);
        mid[row][j] = fmaxf(s, 0.f);
    }
    __syncthreads();
    if (threadIdx.x < RB * 3) {
        const int row = threadIdx.x / 3, k = threadIdx.x - row * 3;
        float o = b2[k];
        const float* wr = W2 + (size_t)k * 64;
#pragma unroll 8
        for (int j = 0; j < 64; j++) o = fmaf(mid[row][j], wr[j], o);
        out[(size_t)(b0 + row) * 3 + k] = o;
    }
}

extern "C" void kernel_launch(void* const* d_in, const int* in_sizes, int n_in,
                              void* d_out, int out_size, void* d_ws, size_t ws_size,
                              hipStream_t stream) {
    const float* x     = (const float*)d_in[0];
    const float* W_ih0 = (const float*)d_in[1];
    const float* W_hh0 = (const float*)d_in[2];
    const float* b_ih0 = (const float*)d_in[3];
    const float* b_hh0 = (const float*)d_in[4];
    const float* W_ih1 = (const float*)d_in[5];
    const float* W_hh1 = (const float*)d_in[6];
    const float* b_ih1 = (const float*)d_in[7];
    const float* b_hh1 = (const float*)d_in[8];
    const float* W1    = (const float*)d_in[9];
    const float* b1    = (const float*)d_in[10];
    const float* W2    = (const float*)d_in[11];
    const float* b2    = (const float*)d_in[12];
    float* out = (float*)d_out;

    // workspace: xb bf16[256*512*64] @0 (16 MB)
    unsigned short* xb = (unsigned short*)d_ws;

    conv_x_kernel<<<8192, 256, 0, stream>>>(x, xb, (BATCH * SEQ * INDIM) / 4);
    lstm_fused_kernel<<<NTILE, 1024, 0, stream>>>(xb, W_ih0, W_hh0, b_ih0, b_hh0,
                                                  W_ih1, W_hh1, b_ih1, b_hh1,
                                                  W1, b1, W2, b2, out);
}

// Round 3
// 472.621 us; speedup vs baseline: 9.6378x; 9.6378x over previous
//
#include <hip/hip_runtime.h>
#include <hip/hip_bf16.h>
#include <stdint.h>

// Problem dims
#define BATCH 256
#define SEQ   512
#define INDIM 64
#define H     128
#define RB    4               // batch rows per block (valid C-rows at quad*4, r=0)
#define NTILE (BATCH / RB)    // 64 batch tiles per layer
#define CH    16              // pipeline handoff chunk (steps)
#define NCH   (SEQ / CH)

using short8  = __attribute__((ext_vector_type(8))) short;  // 8 bf16 MFMA A/B frag
using float4v = __attribute__((ext_vector_type(4))) float;  // MFMA C/D frag

#define LOG2E 1.4426950408889634f

__device__ __forceinline__ unsigned short f2bf(float f) {
    union { float f; uint32_t u; } v; v.f = f;
    uint32_t u = v.u;
    return (unsigned short)((u + 0x7FFFu + ((u >> 16) & 1u)) >> 16); // RNE
}

__device__ __forceinline__ float fast_exp2(float x) {
#if __has_builtin(__builtin_amdgcn_exp2f)
    return __builtin_amdgcn_exp2f(x);
#else
    return __expf(x * 0.6931471805599453f);
#endif
}
__device__ __forceinline__ float fast_rcp(float x) {
#if __has_builtin(__builtin_amdgcn_rcpf)
    return __builtin_amdgcn_rcpf(x);
#else
    return 1.f / x;
#endif
}
__device__ __forceinline__ float sigmoid_fast(float x) {
    return fast_rcp(1.f + fast_exp2(-LOG2E * x));
}
__device__ __forceinline__ float tanh_fast(float x) {
    return fmaf(-2.f, fast_rcp(1.f + fast_exp2((2.f * LOG2E) * x)), 1.f);
}

// In-step barrier: LDS ordering only (lgkmcnt). Global prefetch loads and
// producer h-stores stay in flight across it. Full __syncthreads (vmcnt
// drain) only at chunk boundaries.
__device__ __forceinline__ void light_barrier() {
    asm volatile("s_waitcnt lgkmcnt(0)\n\ts_barrier" ::: "memory");
}

// ---------------- x fp32 -> bf16 convert (+ flag zeroing) ----------------
__global__ void conv_x_kernel(const float* __restrict__ x,
                              unsigned short* __restrict__ xb, int n4,
                              int* __restrict__ flags) {
    int i = blockIdx.x * blockDim.x + threadIdx.x;
    if (blockIdx.x == 0 && threadIdx.x < NTILE) flags[threadIdx.x] = 0;
    if (i >= n4) return;
    float4 f = ((const float4*)x)[i];
    ushort4 o;
    o.x = f2bf(f.x); o.y = f2bf(f.y); o.z = f2bf(f.z); o.w = f2bf(f.w);
    ((ushort4*)xb)[i] = o;
}

// ---------------- fused 2-layer pipelined LSTM + head ----------------
// 128 blocks x 512 threads (R0 skeleton, the 442us verified structure).
// Blocks 0..63: layer0 (producer), 64..127: layer1 (consumer), paired on
// batch tile bt via chunked flag handoff through global h0sq.
//
// R2 lesson (hard constraint): register-persistent weights are 96-128
// VGPRs/wave -> max 2 waves/SIMD (256-reg budget). 4-waves/SIMD designs
// spill catastrophically (133MB scratch fetch). Therefore the only lever is
// the per-step serial critical path, not occupancy.
//
// R3 changes vs R0:
//  (1) depth-2 MFMA chains: gate accumulation split into accA (k-tiles 0,1)
//      + accB (k-tiles 2,3); only element [0] is ever read, so the merge is
//      one v_add per gate. Cuts the post-ds_read dependent-MFMA segment
//      from ~4x40 to ~2x40 cyc.
//  (2) in-step accumulators: bias-seed + x-projection MFMAs run at step
//      start from prefetched x regs (off the critical path, hidden under
//      the h ds_read latency) instead of the cross-barrier accNext double
//      buffer. Acc live range no longer spans the barrier (-32 persistent
//      AGPRs).
//  (3) v_cvt_pk_bf16_f32 (single-instr RNE, bit-identical to f2bf) on the
//      critical h->LDS tail.
// R5 lesson (still enforced): every per-thread register array is indexed
// ONLY with compile-time constants; x double buffer is statically named
// (xf0/xf1) via the unroll-by-2 step loop.
template<int KIN, bool IS_PROD>
__device__ __forceinline__ void lstm_body(
    const unsigned short* __restrict__ xin,  // [BATCH][SEQ][KIN] bf16
    const float* __restrict__ Wih,           // [4H][KIN]
    const float* __restrict__ Whh,           // [4H][H]
    const float* __restrict__ b_ih, const float* __restrict__ b_hh,
    unsigned short* __restrict__ outseq,     // producer: [BATCH][SEQ][H] bf16
    const float* __restrict__ W1, const float* __restrict__ b1,
    const float* __restrict__ W2, const float* __restrict__ b2,
    float* __restrict__ out,                 // consumer: [BATCH][3]
    int* flag, int bt)
{
    constexpr int KT  = KIN / 32;
    constexpr int PAD = 132;                 // 66 dwords == 2 mod 32 -> 2-way (free) aliasing
    const int lane = threadIdx.x & 63;
    const int quad = lane >> 4;
    const int l16  = lane & 15;
    const int b0   = bt * RB;
    const int cell = (threadIdx.x >> 6) * 16 + l16;
    const int arow = l16 & 12;               // LDS h row this lane reads (4-lane broadcast)
    const int xrow = b0 + (l16 >> 2);        // batch row this lane loads (duplicated 4x)

    __shared__ short hbuf[2][16][PAD];
    __shared__ float hl[RB][128];            // fp32 h_last (consumer head input)
    __shared__ float mid[RB][65];
    for (int i = threadIdx.x; i < 2 * 16 * PAD; i += 512) ((short*)hbuf)[i] = 0;

    // ---- weight fragments (loaded once, fp32->bf16, persist in registers) ----
    short8 whh_f[4][4];
    short8 wih_f[4][KT];
    float  bias[4];
#pragma unroll
    for (int tT = 0; tT < 4; tT++) {
        const int n = tT * 128 + cell;
#pragma unroll
        for (int kt = 0; kt < 4; kt++) {
            const float* p = Whh + (size_t)n * H + kt * 32 + quad * 8;
            float4 f0 = *(const float4*)p;
            float4 f1 = *(const float4*)(p + 4);
            short8 s;
            s[0]=f2bf(f0.x); s[1]=f2bf(f0.y); s[2]=f2bf(f0.z); s[3]=f2bf(f0.w);
            s[4]=f2bf(f1.x); s[5]=f2bf(f1.y); s[6]=f2bf(f1.z); s[7]=f2bf(f1.w);
            whh_f[tT][kt] = s;
        }
#pragma unroll
        for (int kt = 0; kt < KT; kt++) {
            const float* p = Wih + (size_t)n * KIN + kt * 32 + quad * 8;
            float4 f0 = *(const float4*)p;
            float4 f1 = *(const float4*)(p + 4);
            short8 s;
            s[0]=f2bf(f0.x); s[1]=f2bf(f0.y); s[2]=f2bf(f0.z); s[3]=f2bf(f0.w);
            s[4]=f2bf(f1.x); s[5]=f2bf(f1.y); s[6]=f2bf(f1.z); s[7]=f2bf(f1.w);
            wih_f[tT][kt] = s;
        }
        bias[tT] = b_ih[n] + b_hh[n];
    }

    float c0 = 0.f;                          // this lane's single cell state

    const unsigned short* xp = xin + ((size_t)xrow * SEQ) * KIN + quad * 8;
    unsigned short* op = nullptr;
    if (IS_PROD)
        op = outseq + ((size_t)(b0 + quad) * SEQ) * H + cell;

    short8 xf0[KT], xf1[KT];                 // statically-named x double buffer
    __syncthreads();                         // hbuf zero-init visible

    // One step. CUR is compile-time after inlining. Consumes xf (holds x(t)),
    // reloads xf with x(t+2) right after the x-MFMAs (depth-2 prefetch: xf's
    // next use is ~1.5 steps away, > HBM latency). Gate math:
    //   accA = bias + x(kt 0,1) + h(kt 0,1)   [depth-2 h chain]
    //   accB =        x(kt 2,3) + h(kt 2,3)   [depth-2 h chain]
    //   g = accA[0] + accB[0]
    auto step = [&](int t, int CUR, short8 (&xf)[KT],
                    bool doPre) __attribute__((always_inline)) {
        short8 ha[4];
#pragma unroll
        for (int kt = 0; kt < 4; kt++)
            ha[kt] = *(const short8*)&hbuf[CUR][arow][kt * 32 + quad * 8];

        float4v accA[4], accB[4];            // in-step only (no cross-barrier live range)
#pragma unroll
        for (int tT = 0; tT < 4; tT++) {
            accA[tT] = (float4v){bias[tT], bias[tT], bias[tT], bias[tT]};
            accB[tT] = (float4v){0.f, 0.f, 0.f, 0.f};
        }
        // x-projection from prefetched regs: fills the ds_read latency window
#pragma unroll
        for (int tT = 0; tT < 4; tT++)
            accA[tT] = __builtin_amdgcn_mfma_f32_16x16x32_bf16(xf[0], wih_f[tT][0], accA[tT], 0, 0, 0);
#pragma unroll
        for (int tT = 0; tT < 4; tT++)
            accA[tT] = __builtin_amdgcn_mfma_f32_16x16x32_bf16(xf[1], wih_f[tT][1], accA[tT], 0, 0, 0);
        if constexpr (KT == 4) {
#pragma unroll
            for (int tT = 0; tT < 4; tT++)
                accB[tT] = __builtin_amdgcn_mfma_f32_16x16x32_bf16(xf[2], wih_f[tT][2], accB[tT], 0, 0, 0);
#pragma unroll
            for (int tT = 0; tT < 4; tT++)
                accB[tT] = __builtin_amdgcn_mfma_f32_16x16x32_bf16(xf[3], wih_f[tT][3], accB[tT], 0, 0, 0);
        }
        if (doPre) {                         // reload xf = x(t+2) (WAR after use)
            const unsigned short* p = xp + (size_t)(t + 2) * KIN;
#pragma unroll
            for (int kt = 0; kt < KT; kt++) xf[kt] = *(const short8*)(p + kt * 32);
        }
        // recurrent projection: two parallel depth-2 chains
#pragma unroll
        for (int tT = 0; tT < 4; tT++)
            accA[tT] = __builtin_amdgcn_mfma_f32_16x16x32_bf16(ha[0], whh_f[tT][0], accA[tT], 0, 0, 0);
#pragma unroll
        for (int tT = 0; tT < 4; tT++)
            accB[tT] = __builtin_amdgcn_mfma_f32_16x16x32_bf16(ha[2], whh_f[tT][2], accB[tT], 0, 0, 0);
#pragma unroll
        for (int tT = 0; tT < 4; tT++)
            accA[tT] = __builtin_amdgcn_mfma_f32_16x16x32_bf16(ha[1], whh_f[tT][1], accA[tT], 0, 0, 0);
#pragma unroll
        for (int tT = 0; tT < 4; tT++)
            accB[tT] = __builtin_amdgcn_mfma_f32_16x16x32_bf16(ha[3], whh_f[tT][3], accB[tT], 0, 0, 0);

        float g0 = accA[0][0] + accB[0][0];
        float g1 = accA[1][0] + accB[1][0];
        float g2 = accA[2][0] + accB[2][0];
        float g3 = accA[3][0] + accB[3][0];

        float si = sigmoid_fast(g0);
        float sf = sigmoid_fast(g1);
        float tg = tanh_fast(g2);
        float so = sigmoid_fast(g3);
        c0 = fmaf(sf, c0, si * tg);
        float h = so * tanh_fast(c0);
        uint32_t hp;                          // single-instr RNE f32->bf16
        asm("v_cvt_pk_bf16_f32 %0, %1, %2" : "=v"(hp) : "v"(h), "v"(h));
        hbuf[CUR ^ 1][quad * 4][cell] = (short)(hp & 0xffffu);
        if (IS_PROD) {
            *op = (unsigned short)(hp & 0xffffu);  // fire-and-forget; drained at chunk end
            op += H;
        } else if (t == SEQ - 1) {
            hl[quad][cell] = h;
        }
        light_barrier();                     // LDS-only: loads/stores stay in flight
    };

    for (int ch = 0; ch < NCH; ch++) {
        const int t0 = ch * CH;
        if (!IS_PROD) {
            if (threadIdx.x == 0) {
                while (__hip_atomic_load(flag, __ATOMIC_RELAXED, __HIP_MEMORY_SCOPE_AGENT) <= ch)
                    __builtin_amdgcn_s_sleep(2);
                (void)__hip_atomic_load(flag, __ATOMIC_ACQUIRE, __HIP_MEMORY_SCOPE_AGENT);
            }
            __syncthreads();
        }
        // chunk fill: consumer every chunk (x not readable across the flag);
        // producer only once (its depth-2 reload pipeline runs across chunks)
        if (!IS_PROD || ch == 0) {
            const unsigned short* p0 = xp + (size_t)t0 * KIN;
            const unsigned short* p1 = p0 + KIN;
#pragma unroll
            for (int kt = 0; kt < KT; kt++) {
                xf0[kt] = *(const short8*)(p0 + kt * 32);
                xf1[kt] = *(const short8*)(p1 + kt * 32);
            }
        }

#pragma unroll 1
        for (int i = 0; i < CH; i += 2) {
            const int t = t0 + i;
            const bool pre0 = IS_PROD ? (t + 2 < SEQ) : (i + 2 < CH);
            const bool pre1 = IS_PROD ? (t + 3 < SEQ) : (i + 3 < CH);
            step(t,     0, xf0, pre0);       // even -> reads hbuf[0], writes hbuf[1]
            step(t + 1, 1, xf1, pre1);       // odd  -> reads hbuf[1], writes hbuf[0]
        }
        __syncthreads();                     // vmcnt drain (producer stores) + boundary
        if (IS_PROD && threadIdx.x == 0)
            __hip_atomic_fetch_add(flag, 1, __ATOMIC_RELEASE, __HIP_MEMORY_SCOPE_AGENT);
    }

    if (!IS_PROD) {
        // ---- MLP head for this block's RB rows (hl visible via last barrier)
        if (threadIdx.x < RB * 64) {
            const int row = threadIdx.x >> 6, j = threadIdx.x & 63;
            float s = b1[j];
            const float* wr = W1 + (size_t)j * 128;
#pragma unroll 8
            for (int k = 0; k < 128; k++) s = fmaf(hl[row][k], wr[k], s);
            mid[row][j] = fmaxf(s, 0.f);
        }
        __syncthreads();
        if (threadIdx.x < RB * 3) {
            const int row = threadIdx.x / 3, k = threadIdx.x - row * 3;
            float o = b2[k];
            const float* wr = W2 + (size_t)k * 64;
#pragma unroll 8
            for (int j = 0; j < 64; j++) o = fmaf(mid[row][j], wr[j], o);
            out[(size_t)(b0 + row) * 3 + k] = o;
        }
    }
}

__global__ __launch_bounds__(512, 2)
void lstm_fused_kernel(const unsigned short* __restrict__ xb,
                       const float* __restrict__ Wih0, const float* __restrict__ Whh0,
                       const float* __restrict__ bih0, const float* __restrict__ bhh0,
                       const float* __restrict__ Wih1, const float* __restrict__ Whh1,
                       const float* __restrict__ bih1, const float* __restrict__ bhh1,
                       unsigned short* __restrict__ h0sq,
                       const float* __restrict__ W1, const float* __restrict__ b1,
                       const float* __restrict__ W2, const float* __restrict__ b2,
                       float* __restrict__ out,
                       int* __restrict__ flags)
{
    const int bt = blockIdx.x & (NTILE - 1);
    if (blockIdx.x < NTILE)
        lstm_body<64,  true >(xb,   Wih0, Whh0, bih0, bhh0, h0sq,
                              W1, b1, W2, b2, out, flags + bt, bt);
    else
        lstm_body<128, false>(h0sq, Wih1, Whh1, bih1, bhh1, nullptr,
                              W1, b1, W2, b2, out, flags + bt, bt);
}

extern "C" void kernel_launch(void* const* d_in, const int* in_sizes, int n_in,
                              void* d_out, int out_size, void* d_ws, size_t ws_size,
                              hipStream_t stream) {
    const float* x     = (const float*)d_in[0];
    const float* W_ih0 = (const float*)d_in[1];
    const float* W_hh0 = (const float*)d_in[2];
    const float* b_ih0 = (const float*)d_in[3];
    const float* b_hh0 = (const float*)d_in[4];
    const float* W_ih1 = (const float*)d_in[5];
    const float* W_hh1 = (const float*)d_in[6];
    const float* b_ih1 = (const float*)d_in[7];
    const float* b_hh1 = (const float*)d_in[8];
    const float* W1    = (const float*)d_in[9];
    const float* b1    = (const float*)d_in[10];
    const float* W2    = (const float*)d_in[11];
    const float* b2    = (const float*)d_in[12];
    float* out = (float*)d_out;

    // workspace: xb bf16[256*512*64] @0 (16 MB); h0sq bf16[256*512*128] @16 MB (32 MB); flags @48 MB
    char* ws = (char*)d_ws;
    unsigned short* xb    = (unsigned short*)ws;
    unsigned short* h0sq  = (unsigned short*)(ws + 16777216);
    int*            flags = (int*)(ws + 50331648);

    conv_x_kernel<<<8192, 256, 0, stream>>>(x, xb, (BATCH * SEQ * INDIM) / 4, flags);
    lstm_fused_kernel<<<2 * NTILE, 512, 0, stream>>>(xb, W_ih0, W_hh0, b_ih0, b_hh0,
                                                     W_ih1, W_hh1, b_ih1, b_hh1,
                                                     h0sq, W1, b1, W2, b2, out, flags);
}